// Round 1
// baseline (485.750 us; speedup 1.0000x reference)
//
#include <hip/hip_runtime.h>

// x: (4, 32, 512, 512) fp32; bias: (1,32,1,1) fp32
// out: G1 | G2 | G3 concatenated, each (4,32,512,512) fp32
//
// G1[h,w] = (h>=1 && w>=1) ? exp(-(x[h-1,w-1]-x[h,w])^2)+b : b
// G2[h,w] = (w>=1)          ? exp(-(x[h,w-1]  -x[h,w])^2)+b : b
// G3[h,w] = (h<=510 && w>=1)? exp(-(x[h+1,w-1]-x[h,w])^2)+b : b
//
// Streaming roofline: 128 MiB read + 384 MiB write => ~85 us at 6.3 TB/s.
//
// Structure: column-strip register rotation. Each thread owns 4 columns
// (one float4) and walks ROWS_PT=16 rows, keeping rows h-1/h/h+1 in
// registers. One float4 load per output row (vs 6 vmem loads/row in the
// previous version). x[*, w0-1] comes from __shfl_up of the left lane's
// .w (wave-lane 0 does a 1-lane predicated load). Next-next row is
// prefetched one iteration ahead. Nontemporal loads+stores: x has ~no
// cross-thread reuse in this layout, and the 402 MB of stores must not
// evict anything.

#define IMG_W 512
#define IMG_H 512
#define PLANE (IMG_W * IMG_H)
#define N_IMG 128            // 4 * 32
#define N_ELEM (N_IMG * PLANE)
#define ROWS_PT 16
#define CHUNKS (IMG_H / ROWS_PT)   // 32

typedef float f32x4 __attribute__((ext_vector_type(4)));

__global__ __launch_bounds__(256)
void embeded_gate_kernel(const float* __restrict__ x,
                         const float* __restrict__ bias,
                         float* __restrict__ out) {
    const int s     = blockIdx.x * blockDim.x + threadIdx.x;
    const int w4    = s & 127;          // float4 group within row
    const int chunk = (s >> 7) & (CHUNKS - 1);
    const int img   = s >> 12;          // n*32 + c   (4096 strips per image)
    const int w0    = w4 << 2;
    const int hs    = chunk * ROWS_PT;

    const float b = bias[img & 31];
    const float* __restrict__ xp = x + img * PLANE;

    // wave-lane 0 (w4 == 0 or 64) can't shuffle x[w0-1] from a neighbor
    const bool need_m = ((threadIdx.x & 63) == 0) & (w0 > 0);

    // coalesced 1 KB/wave vector load of one row segment
    auto ld4 = [&](int r) -> f32x4 {
        return __builtin_nontemporal_load(
            reinterpret_cast<const f32x4*>(xp + r * IMG_W + w0));
    };
    // x[r, w0-1]: lane l takes lane (l-1)'s .w; wave-lane 0 loads it
    auto ldm = [&](f32x4 v, int r) -> float {
        float m = __shfl_up(v[3], 1);
        if (need_m) m = xp[r * IMG_W + w0 - 1];
        return m;
    };

    const int r_prev = (hs > 0) ? hs - 1 : 0;      // clamped; masked at h==0
    f32x4 p4 = ld4(r_prev);
    f32x4 c4 = ld4(hs);
    f32x4 n4 = ld4(hs + 1);                        // hs <= 496, always valid
    float pm = ldm(p4, r_prev);
    float cm = ldm(c4, hs);
    float nm = ldm(n4, hs + 1);

    int o = img * PLANE + hs * IMG_W + w0;

#pragma unroll
    for (int i = 0; i < ROWS_PT; ++i) {
        const int h  = hs + i;
        const int rf = (h + 2 < IMG_H) ? h + 2 : IMG_H - 1;  // prefetch row
        const f32x4 f4 = ld4(rf);   // issued a full iteration before use

        const bool hok_u = (h > 0);
        const bool hok_d = (h < IMG_H - 1);

        const float us[4] = {pm, p4[0], p4[1], p4[2]};
        const float cs[4] = {cm, c4[0], c4[1], c4[2]};
        const float ds[4] = {nm, n4[0], n4[1], n4[2]};
        const float cc[4] = {c4[0], c4[1], c4[2], c4[3]};

        f32x4 g1, g2, g3;
#pragma unroll
        for (int j = 0; j < 4; ++j) {
            const bool wok = (w0 + j) > 0;   // only j==0 of w4==0 fails
            float d1 = us[j] - cc[j];
            float d2 = cs[j] - cc[j];
            float d3 = ds[j] - cc[j];
            float e1 = __expf(-d1 * d1);
            float e2 = __expf(-d2 * d2);
            float e3 = __expf(-d3 * d3);
            g1[j] = (hok_u & wok) ? e1 + b : b;
            g2[j] = wok           ? e2 + b : b;
            g3[j] = (hok_d & wok) ? e3 + b : b;
        }

        __builtin_nontemporal_store(g1, reinterpret_cast<f32x4*>(out + o));
        __builtin_nontemporal_store(g2, reinterpret_cast<f32x4*>(out + N_ELEM + o));
        __builtin_nontemporal_store(g3, reinterpret_cast<f32x4*>(out + 2 * N_ELEM + o));
        o += IMG_W;

        // rotate; defer the shuffle of f4 to here so the load has a full
        // compute phase to land before the lgkmcnt/vmcnt wait
        p4 = c4; pm = cm;
        c4 = n4; cm = nm;
        n4 = f4; nm = ldm(f4, rf);
    }
}

extern "C" void kernel_launch(void* const* d_in, const int* in_sizes, int n_in,
                              void* d_out, int out_size, void* d_ws, size_t ws_size,
                              hipStream_t stream) {
    const float* x    = (const float*)d_in[0];
    const float* bias = (const float*)d_in[1];
    float* out        = (float*)d_out;

    // 128 imgs * 32 chunks * 128 float4-strips = 524,288 threads
    const int total_threads = N_IMG * CHUNKS * (IMG_W / 4);
    const int block = 256;
    const int grid  = total_threads / block;   // 2048 = 8 blocks/CU exactly
    embeded_gate_kernel<<<grid, block, 0, stream>>>(x, bias, out);
}

// Round 2
// 485.178 us; speedup vs baseline: 1.0012x; 1.0012x over previous
//
#include <hip/hip_runtime.h>

// x: (4, 32, 512, 512) fp32; bias: (1,32,1,1) fp32
// out: G1 | G2 | G3 concatenated, each (4,32,512,512) fp32
//
// G1[h,w] = (h>=1 && w>=1) ? exp(-(x[h-1,w-1]-x[h,w])^2)+b : b
// G2[h,w] = (w>=1)          ? exp(-(x[h,w-1]  -x[h,w])^2)+b : b
// G3[h,w] = (h<=510 && w>=1)? exp(-(x[h+1,w-1]-x[h,w])^2)+b : b
//
// Streaming roofline: 128 MiB read + 384 MiB write => ~85 us at 6.3 TB/s.
//
// ROW-SKEWED STORES: the three output streams are exactly 2^27 B apart, so
// same-row stores hit the same TCC slice / HBM channel / bank (only bits
// >=27 differ -> invisible to the interleave). Each wave dumping 3 KB on
// one bank as three different DRAM rows forces row cycling. Fix: from the
// rotation window (p4=h-1, c4=h, n4=h+1) emit G2[h], G1[h+1], G3[h-1] in
// the same iteration -> stream addresses differ by +-2 KB, landing in
// different banks/slices. All three gates use the SAME shifted current
// row (cs) vs p4/c4/n4 unshifted, so only one shuffle per row is needed:
//   G1[h+1,w] = exp(-(x[h,w-1]-x[h+1,w])^2)   -> cs vs n4
//   G2[h  ,w] = exp(-(x[h,w-1]-x[h  ,w])^2)   -> cs vs c4
//   G3[h-1,w] = exp(-(x[h,w-1]-x[h-1,w])^2)   -> cs vs p4
// Border rows G1[0] and G3[511] are pure bias, written once by edge chunks.

#define IMG_W 512
#define IMG_H 512
#define PLANE (IMG_W * IMG_H)
#define N_IMG 128            // 4 * 32
#define N_ELEM (N_IMG * PLANE)
#define ROWS_PT 16
#define CHUNKS (IMG_H / ROWS_PT)   // 32

typedef float f32x4 __attribute__((ext_vector_type(4)));

__global__ __launch_bounds__(256)
void embeded_gate_kernel(const float* __restrict__ x,
                         const float* __restrict__ bias,
                         float* __restrict__ out) {
    const int s     = blockIdx.x * blockDim.x + threadIdx.x;
    const int w4    = s & 127;          // float4 group within row
    const int chunk = (s >> 7) & (CHUNKS - 1);
    const int img   = s >> 12;          // n*32 + c
    const int w0    = w4 << 2;
    const int hs    = chunk * ROWS_PT;

    const float b = bias[img & 31];
    const float* __restrict__ xp = x + img * PLANE;

    // wave-lane 0 can't shuffle x[w0-1] from a neighbor lane
    const bool need_m = ((threadIdx.x & 63) == 0) & (w0 > 0);

    auto ld4 = [&](int r) -> f32x4 {
        return __builtin_nontemporal_load(
            reinterpret_cast<const f32x4*>(xp + r * IMG_W + w0));
    };
    // x[r, w0-1]: lane l takes lane (l-1)'s .w; wave-lane 0 loads it
    auto ldm = [&](f32x4 v, int r) -> float {
        float m = __shfl_up(v[3], 1);
        if (need_m) m = xp[r * IMG_W + w0 - 1];
        return m;
    };

    const int r_prev = (hs > 0) ? hs - 1 : 0;      // clamped; G3 masked at h==0
    f32x4 p4 = ld4(r_prev);
    f32x4 c4 = ld4(hs);
    f32x4 n4 = ld4(hs + 1);                        // hs+1 <= 497, valid
    float cm = ldm(c4, hs);

    float* __restrict__ o1 = out + img * PLANE;              // G1
    float* __restrict__ o2 = out + N_ELEM + img * PLANE;     // G2
    float* __restrict__ o3 = out + 2 * N_ELEM + img * PLANE; // G3

    // pure-bias border rows, written once per (img, strip)
    if (hs == 0) {
        f32x4 bb = {b, b, b, b};
        __builtin_nontemporal_store(bb, reinterpret_cast<f32x4*>(o1 + w0));
    }
    if (hs == IMG_H - ROWS_PT) {
        f32x4 bb = {b, b, b, b};
        __builtin_nontemporal_store(
            bb, reinterpret_cast<f32x4*>(o3 + (IMG_H - 1) * IMG_W + w0));
    }

#pragma unroll
    for (int i = 0; i < ROWS_PT; ++i) {
        const int h  = hs + i;
        const int rf = (h + 2 < IMG_H) ? h + 2 : IMG_H - 1;  // next n4's row
        const f32x4 f4 = ld4(rf);   // issued a full iteration before use

        const float cs[4] = {cm, c4[0], c4[1], c4[2]};   // x[h, w0-1..w0+2]

        f32x4 g1, g2, g3;
#pragma unroll
        for (int j = 0; j < 4; ++j) {
            const bool wok = (w0 + j) > 0;   // only j==0 of w4==0 fails
            float d1 = cs[j] - n4[j];        // -> G1 row h+1
            float d2 = cs[j] - c4[j];        // -> G2 row h
            float d3 = cs[j] - p4[j];        // -> G3 row h-1
            float e1 = __expf(-d1 * d1);
            float e2 = __expf(-d2 * d2);
            float e3 = __expf(-d3 * d3);
            g1[j] = wok ? e1 + b : b;
            g2[j] = wok ? e2 + b : b;
            g3[j] = wok ? e3 + b : b;
        }

        __builtin_nontemporal_store(
            g2, reinterpret_cast<f32x4*>(o2 + h * IMG_W + w0));
        if (h + 1 < IMG_H)        // G1 row 512 doesn't exist
            __builtin_nontemporal_store(
                g1, reinterpret_cast<f32x4*>(o1 + (h + 1) * IMG_W + w0));
        if (h >= 1)               // G3 row -1 doesn't exist
            __builtin_nontemporal_store(
                g3, reinterpret_cast<f32x4*>(o3 + (h - 1) * IMG_W + w0));

        // rotate window; new c4 is row min(h+1, 511)
        p4 = c4;
        c4 = n4;
        cm = ldm(c4, (h + 1 < IMG_H) ? h + 1 : IMG_H - 1);
        n4 = f4;
    }
}

extern "C" void kernel_launch(void* const* d_in, const int* in_sizes, int n_in,
                              void* d_out, int out_size, void* d_ws, size_t ws_size,
                              hipStream_t stream) {
    const float* x    = (const float*)d_in[0];
    const float* bias = (const float*)d_in[1];
    float* out        = (float*)d_out;

    // 128 imgs * 32 chunks * 128 float4-strips = 524,288 threads
    const int total_threads = N_IMG * CHUNKS * (IMG_W / 4);
    const int block = 256;
    const int grid  = total_threads / block;   // 2048 = 8 blocks/CU exactly
    embeded_gate_kernel<<<grid, block, 0, stream>>>(x, bias, out);
}